// Round 8
// baseline (131.876 us; speedup 1.0000x reference)
//
#include <hip/hip_runtime.h>

// CliffordLayerNorm: per-256-float block, per-grade (popcount) layernorm.
// One wave handles 16 MV blocks (4 lanes each). Lane l (0..3) of a group
// holds the 64 elements m = 16k + 4l + j; popcount(m) = pc(k)+pc(l)+pc(j).
// Per-grade sums reduced with a 2-step Pascal butterfly over the 2 lane bits.
//
// Round-8: R5 structure restored (best: 97 us) -- flat kernel, 2 consecutive
// tasks/wave, plain HIP loads, sched_barrier(0) after the load block. The
// compiler's partial prefetch (VGPR=80: ~half of B hoisted) beat both no
// prefetch (R4: 119 us) and asm-pinned full prefetch (R7: 129 us, occupancy
// halved) -- prefetch depth trades against TLP, and the compiler's balance
// won. One change vs R5: NORMAL stores instead of nontemporal. R1/R2 WRITE
// = 268 MB exact vs R4/R5 NT = 287-309 MB (+14% inflation, no FETCH gain).

typedef float f32x4 __attribute__((ext_vector_type(4)));

static __device__ __forceinline__ float shx(float v, int m) {
    return __shfl_xor(v, m, 64);
}

// Pascal merge over lane bit BM: b[j] = hi ? a[j-1] : a[j] (a[-1]=a[L]=0),
// then a'[j] = b[j] + partner(b[j]). Length L -> L+1.
template <int BM, int L>
static __device__ __forceinline__ void pascal_step(float (&s)[9], float (&q)[9],
                                                   bool hi) {
#pragma unroll
    for (int j = L; j >= 0; --j) {
        float bs = (j == 0) ? (hi ? 0.0f : s[0])
                 : (j == L) ? (hi ? s[L - 1] : 0.0f)
                            : (hi ? s[j - 1] : s[j]);
        float bq = (j == 0) ? (hi ? 0.0f : q[0])
                 : (j == L) ? (hi ? q[L - 1] : 0.0f)
                            : (hi ? q[j - 1] : q[j]);
        s[j] = bs;
        q[j] = bq;
    }
#pragma unroll
    for (int j = 0; j <= L; ++j) {
        s[j] += shx(s[j], BM);
        q[j] += shx(q[j], BM);
    }
}

static __device__ __forceinline__ void process_task(
    const f32x4 (&xv)[16], float* __restrict__ out, int blk, int l,
    bool p1, bool p2, bool hi1, bool hi2,
    const float (&wg)[9], const float (&bg)[9])
{
    constexpr int PC[16] = {0,1,1,2,1,2,2,3,1,2,2,3,2,3,3,4};
    const float invc[9] = {1.0f, 0.125f, 1.0f/28.0f, 1.0f/56.0f, 1.0f/70.0f,
                           1.0f/56.0f, 1.0f/28.0f, 0.125f, 1.0f};

    float s[9], q[9];
#pragma unroll
    for (int j = 0; j < 9; ++j) { s[j] = 0.0f; q[j] = 0.0f; }

#define ACC1(v, r) { s[r] += (v); q[r] = fmaf((v), (v), q[r]); }
#pragma unroll
    for (int k = 0; k < 16; ++k) {
        const int r = PC[k];
        ACC1(xv[k][0], r + 0)
        ACC1(xv[k][1], r + 1)
        ACC1(xv[k][2], r + 1)
        ACC1(xv[k][3], r + 2)
    }
#undef ACC1

    pascal_step<1, 7>(s, q, hi1);
    pascal_step<2, 8>(s, q, hi2);

    float scl[9], sft[9];
#pragma unroll
    for (int g = 0; g < 9; ++g) {
        float mean = s[g] * invc[g];
        float var  = fmaf(-mean, mean, q[g] * invc[g]);
        var = fmaxf(var, 0.0f);
        float inv = rsqrtf(var + 1e-5f);
        float sc  = inv * wg[g];
        scl[g] = sc;
        sft[g] = fmaf(-mean, sc, bg[g]);
    }

    // shift down by p = pc(l) in 0..2; only relative grades 0..6 consumed
#pragma unroll
    for (int j = 0; j < 7; ++j) { scl[j] = p2 ? scl[j+2] : scl[j];
                                  sft[j] = p2 ? sft[j+2] : sft[j]; }
#pragma unroll
    for (int j = 0; j < 7; ++j) { scl[j] = p1 ? scl[j+1] : scl[j];
                                  sft[j] = p1 ? sft[j+1] : sft[j]; }

    f32x4* ob = reinterpret_cast<f32x4*>(out) + (size_t)blk * 64;
#pragma unroll
    for (int k = 0; k < 16; ++k) {
        const int r = PC[k];
        f32x4 o;
        o[0] = fmaf(xv[k][0], scl[r + 0], sft[r + 0]);
        o[1] = fmaf(xv[k][1], scl[r + 1], sft[r + 1]);
        o[2] = fmaf(xv[k][2], scl[r + 1], sft[r + 1]);
        o[3] = fmaf(xv[k][3], scl[r + 2], sft[r + 2]);
        ob[4 * k + l] = o;
    }
}

#define LOADT(buf, task) { \
    const f32x4* xb = reinterpret_cast<const f32x4*>(x) + \
        ((size_t)(((task) << 4) + grp)) * 64; \
    _Pragma("unroll") \
    for (int k = 0; k < 16; ++k) buf[k] = xb[4 * k + l]; }

// Fast path: ntask even, one wave per 2 consecutive tasks.
__global__ __launch_bounds__(256) void cliff_ln_flat(
    const float* __restrict__ x, const float* __restrict__ w,
    const float* __restrict__ b, float* __restrict__ out, int nwaves)
{
    const int lane = threadIdx.x & 63;
    const int grp  = lane >> 2;
    const int l    = lane & 3;
    const int p    = __popc(l);
    const bool p1 = (p & 1) != 0, p2 = (p & 2) != 0;
    const bool hi1 = (l & 1) != 0, hi2 = (l & 2) != 0;
    const int wid = (blockIdx.x * blockDim.x + threadIdx.x) >> 6;
    if (wid >= nwaves) return;
    const int tA = wid * 2, tB = tA + 1;

    float wg[9], bg[9];
#pragma unroll
    for (int g = 0; g < 9; ++g) { wg[g] = w[g]; bg[g] = b[g]; }

    f32x4 A[16], B[16];
    LOADT(A, tA)
    LOADT(B, tB)
    __builtin_amdgcn_sched_barrier(0);
    process_task(A, out, (tA << 4) + grp, l, p1, p2, hi1, hi2, wg, bg);
    process_task(B, out, (tB << 4) + grp, l, p1, p2, hi1, hi2, wg, bg);
}

// General fallback: grid-stride, 1 task per wave.
__global__ __launch_bounds__(256) void cliff_ln_loop(
    const float* __restrict__ x, const float* __restrict__ w,
    const float* __restrict__ b, float* __restrict__ out, int ntask)
{
    const int lane = threadIdx.x & 63;
    const int grp  = lane >> 2;
    const int l    = lane & 3;
    const int p    = __popc(l);
    const bool p1 = (p & 1) != 0, p2 = (p & 2) != 0;
    const bool hi1 = (l & 1) != 0, hi2 = (l & 2) != 0;
    const int wave_id     = (blockIdx.x * blockDim.x + threadIdx.x) >> 6;
    const int total_waves = (gridDim.x * blockDim.x) >> 6;

    float wg[9], bg[9];
#pragma unroll
    for (int g = 0; g < 9; ++g) { wg[g] = w[g]; bg[g] = b[g]; }

    for (int task = wave_id; task < ntask; task += total_waves) {
        f32x4 A[16];
        LOADT(A, task)
        process_task(A, out, (task << 4) + grp, l, p1, p2, hi1, hi2, wg, bg);
    }
}

#undef LOADT

extern "C" void kernel_launch(void* const* d_in, const int* in_sizes, int n_in,
                              void* d_out, int out_size, void* d_ws, size_t ws_size,
                              hipStream_t stream) {
    const float* x = (const float*)d_in[0];
    const float* w = (const float*)d_in[1];
    const float* b = (const float*)d_in[2];
    float* out = (float*)d_out;
    const int n = in_sizes[0];
    const int nblk = n / 256;
    const int ntask = nblk / 16;            // 16384 for the bench shape

    if ((nblk % 16 == 0) && (ntask % 2 == 0)) {
        const int nwaves = ntask / 2;       // 8192
        const int wgs = (nwaves + 3) / 4;   // 2048 WGs
        hipLaunchKernelGGL(cliff_ln_flat, dim3(wgs), dim3(256), 0, stream,
                           x, w, b, out, nwaves);
    } else {
        int wgs = (ntask + 3) / 4;
        if (wgs > 8192) wgs = 8192;
        if (wgs < 1) wgs = 1;
        hipLaunchKernelGGL(cliff_ln_loop, dim3(wgs), dim3(256), 0, stream,
                           x, w, b, out, ntask);
    }
}

// Round 9
// 99.083 us; speedup vs baseline: 1.3310x; 1.3310x over previous
//
#include <hip/hip_runtime.h>

// CliffordLayerNorm: per-256-float block, per-grade (popcount) layernorm.
// One wave handles 16 MV blocks (4 lanes each). Lane l (0..3) of a group
// holds the 64 elements m = 16k + 4l + j; popcount(m) = pc(k)+pc(l)+pc(j).
// Per-grade sums reduced with a 2-step Pascal butterfly over the 2 lane bits.
//
// Round-9: NT stores RESTORED -- R8 proved they are a +35% win (R5 97us with
// NT vs R8 132us with normal stores, identical structure): normal stores
// write-allocate in the 4MiB/XCD L2 and thrash it; NT streams past L2,
// preserving it for the read stream. WRITE_SIZE inflation (+14%) is the
// cheaper side of that trade. Structure: R5's flat depth-2 compiler-balanced
// pipeline, extended to 4 consecutive tasks per wave (two depth-2 stages,
// A/B register buffers reused) -> 4096 waves = 16/CU fully co-resident,
// cross-stage load/compute overlap, amortized prologue.

typedef float f32x4 __attribute__((ext_vector_type(4)));

static __device__ __forceinline__ float shx(float v, int m) {
    return __shfl_xor(v, m, 64);
}

// Pascal merge over lane bit BM: b[j] = hi ? a[j-1] : a[j] (a[-1]=a[L]=0),
// then a'[j] = b[j] + partner(b[j]). Length L -> L+1.
template <int BM, int L>
static __device__ __forceinline__ void pascal_step(float (&s)[9], float (&q)[9],
                                                   bool hi) {
#pragma unroll
    for (int j = L; j >= 0; --j) {
        float bs = (j == 0) ? (hi ? 0.0f : s[0])
                 : (j == L) ? (hi ? s[L - 1] : 0.0f)
                            : (hi ? s[j - 1] : s[j]);
        float bq = (j == 0) ? (hi ? 0.0f : q[0])
                 : (j == L) ? (hi ? q[L - 1] : 0.0f)
                            : (hi ? q[j - 1] : q[j]);
        s[j] = bs;
        q[j] = bq;
    }
#pragma unroll
    for (int j = 0; j <= L; ++j) {
        s[j] += shx(s[j], BM);
        q[j] += shx(q[j], BM);
    }
}

static __device__ __forceinline__ void process_task(
    const f32x4 (&xv)[16], float* __restrict__ out, int blk, int l,
    bool p1, bool p2, bool hi1, bool hi2,
    const float (&wg)[9], const float (&bg)[9])
{
    constexpr int PC[16] = {0,1,1,2,1,2,2,3,1,2,2,3,2,3,3,4};
    const float invc[9] = {1.0f, 0.125f, 1.0f/28.0f, 1.0f/56.0f, 1.0f/70.0f,
                           1.0f/56.0f, 1.0f/28.0f, 0.125f, 1.0f};

    float s[9], q[9];
#pragma unroll
    for (int j = 0; j < 9; ++j) { s[j] = 0.0f; q[j] = 0.0f; }

#define ACC1(v, r) { s[r] += (v); q[r] = fmaf((v), (v), q[r]); }
#pragma unroll
    for (int k = 0; k < 16; ++k) {
        const int r = PC[k];
        ACC1(xv[k][0], r + 0)
        ACC1(xv[k][1], r + 1)
        ACC1(xv[k][2], r + 1)
        ACC1(xv[k][3], r + 2)
    }
#undef ACC1

    pascal_step<1, 7>(s, q, hi1);
    pascal_step<2, 8>(s, q, hi2);

    float scl[9], sft[9];
#pragma unroll
    for (int g = 0; g < 9; ++g) {
        float mean = s[g] * invc[g];
        float var  = fmaf(-mean, mean, q[g] * invc[g]);
        var = fmaxf(var, 0.0f);
        float inv = rsqrtf(var + 1e-5f);
        float sc  = inv * wg[g];
        scl[g] = sc;
        sft[g] = fmaf(-mean, sc, bg[g]);
    }

    // shift down by p = pc(l) in 0..2; only relative grades 0..6 consumed
#pragma unroll
    for (int j = 0; j < 7; ++j) { scl[j] = p2 ? scl[j+2] : scl[j];
                                  sft[j] = p2 ? sft[j+2] : sft[j]; }
#pragma unroll
    for (int j = 0; j < 7; ++j) { scl[j] = p1 ? scl[j+1] : scl[j];
                                  sft[j] = p1 ? sft[j+1] : sft[j]; }

    f32x4* ob = reinterpret_cast<f32x4*>(out) + (size_t)blk * 64;
#pragma unroll
    for (int k = 0; k < 16; ++k) {
        const int r = PC[k];
        f32x4 o;
        o[0] = fmaf(xv[k][0], scl[r + 0], sft[r + 0]);
        o[1] = fmaf(xv[k][1], scl[r + 1], sft[r + 1]);
        o[2] = fmaf(xv[k][2], scl[r + 1], sft[r + 1]);
        o[3] = fmaf(xv[k][3], scl[r + 2], sft[r + 2]);
        __builtin_nontemporal_store(o, &ob[4 * k + l]);
    }
}

#define LOADT(buf, task) { \
    const f32x4* xb = reinterpret_cast<const f32x4*>(x) + \
        ((size_t)(((task) << 4) + grp)) * 64; \
    _Pragma("unroll") \
    for (int k = 0; k < 16; ++k) buf[k] = xb[4 * k + l]; }

// Fast path: one wave per 4 consecutive tasks, two depth-2 stages.
__global__ __launch_bounds__(256) void cliff_ln_flat4(
    const float* __restrict__ x, const float* __restrict__ w,
    const float* __restrict__ b, float* __restrict__ out, int nwaves)
{
    const int lane = threadIdx.x & 63;
    const int grp  = lane >> 2;
    const int l    = lane & 3;
    const int p    = __popc(l);
    const bool p1 = (p & 1) != 0, p2 = (p & 2) != 0;
    const bool hi1 = (l & 1) != 0, hi2 = (l & 2) != 0;
    const int wid = (blockIdx.x * blockDim.x + threadIdx.x) >> 6;
    if (wid >= nwaves) return;
    const int t0 = wid * 4;

    float wg[9], bg[9];
#pragma unroll
    for (int g = 0; g < 9; ++g) { wg[g] = w[g]; bg[g] = b[g]; }

    f32x4 A[16], B[16];
    // stage 1
    LOADT(A, t0)
    LOADT(B, t0 + 1)
    __builtin_amdgcn_sched_barrier(0);
    process_task(A, out, ((t0    ) << 4) + grp, l, p1, p2, hi1, hi2, wg, bg);
    process_task(B, out, ((t0 + 1) << 4) + grp, l, p1, p2, hi1, hi2, wg, bg);
    // stage 2 (loads may be hoisted into stage 1's compute by the compiler)
    LOADT(A, t0 + 2)
    LOADT(B, t0 + 3)
    __builtin_amdgcn_sched_barrier(0);
    process_task(A, out, ((t0 + 2) << 4) + grp, l, p1, p2, hi1, hi2, wg, bg);
    process_task(B, out, ((t0 + 3) << 4) + grp, l, p1, p2, hi1, hi2, wg, bg);
}

// General fallback: grid-stride, 1 task per wave.
__global__ __launch_bounds__(256) void cliff_ln_loop(
    const float* __restrict__ x, const float* __restrict__ w,
    const float* __restrict__ b, float* __restrict__ out, int ntask)
{
    const int lane = threadIdx.x & 63;
    const int grp  = lane >> 2;
    const int l    = lane & 3;
    const int p    = __popc(l);
    const bool p1 = (p & 1) != 0, p2 = (p & 2) != 0;
    const bool hi1 = (l & 1) != 0, hi2 = (l & 2) != 0;
    const int wave_id     = (blockIdx.x * blockDim.x + threadIdx.x) >> 6;
    const int total_waves = (gridDim.x * blockDim.x) >> 6;

    float wg[9], bg[9];
#pragma unroll
    for (int g = 0; g < 9; ++g) { wg[g] = w[g]; bg[g] = b[g]; }

    for (int task = wave_id; task < ntask; task += total_waves) {
        f32x4 A[16];
        LOADT(A, task)
        process_task(A, out, (task << 4) + grp, l, p1, p2, hi1, hi2, wg, bg);
    }
}

#undef LOADT

extern "C" void kernel_launch(void* const* d_in, const int* in_sizes, int n_in,
                              void* d_out, int out_size, void* d_ws, size_t ws_size,
                              hipStream_t stream) {
    const float* x = (const float*)d_in[0];
    const float* w = (const float*)d_in[1];
    const float* b = (const float*)d_in[2];
    float* out = (float*)d_out;
    const int n = in_sizes[0];
    const int nblk = n / 256;
    const int ntask = nblk / 16;            // 16384 for the bench shape

    if ((nblk % 16 == 0) && (ntask % 4 == 0)) {
        const int nwaves = ntask / 4;       // 4096
        const int wgs = (nwaves + 3) / 4;   // 1024 WGs
        hipLaunchKernelGGL(cliff_ln_flat4, dim3(wgs), dim3(256), 0, stream,
                           x, w, b, out, nwaves);
    } else {
        int wgs = (ntask + 3) / 4;
        if (wgs > 8192) wgs = 8192;
        if (wgs < 1) wgs = 1;
        hipLaunchKernelGGL(cliff_ln_loop, dim3(wgs), dim3(256), 0, stream,
                           x, w, b, out, ntask);
    }
}

// Round 10
// 85.440 us; speedup vs baseline: 1.5435x; 1.1597x over previous
//
#include <hip/hip_runtime.h>

// CliffordLayerNorm: per-256-float block, per-grade (popcount) layernorm.
// Round-10: 8 lanes per MV block (8 blocks/wave). Lane l (0..7) of a group
// holds the 8 float4s f = 8k + l  ->  elements m = 32k + 4l + j, so
// popcount(m) = pc(k) + pc(l) + pc(j) with k in 0..7, j in 0..3.
// Each lane's elements span relative grades 0..5 above base p = pc(l) (0..3).
// Per-grade sums reduced with a 3-step Pascal butterfly (6 -> 7 -> 8 -> 9).
//
// Why 8 lanes: with 4 lanes/group each load/store instruction covered only
// 64B per group; NT stores bypass L2 merging, so half-lines hit HBM ->
// +14% WRITE_SIZE inflation (307 vs 268 MB) and partial-line (RMW/ECC)
// write cost. 8 lanes/group = 128B fully-aligned lines per instruction.
// NT stores kept (R8 proved +35%: they stop the write stream thrashing L2).
// Structure: R5's flat depth-2 compiler-balanced pipeline (best: 97us),
// now 16384 waves for extra TLP.

typedef float f32x4 __attribute__((ext_vector_type(4)));

static __device__ __forceinline__ float shx(float v, int m) {
    return __shfl_xor(v, m, 64);
}

// Pascal merge over lane bit BM: b[j] = hi ? a[j-1] : a[j] (a[-1]=a[L]=0),
// then a'[j] = b[j] + partner(b[j]). Array length L -> L+1.
template <int BM, int L>
static __device__ __forceinline__ void pascal_step(float (&s)[9], float (&q)[9],
                                                   bool hi) {
#pragma unroll
    for (int j = L; j >= 0; --j) {
        float bs = (j == 0) ? (hi ? 0.0f : s[0])
                 : (j == L) ? (hi ? s[L - 1] : 0.0f)
                            : (hi ? s[j - 1] : s[j]);
        float bq = (j == 0) ? (hi ? 0.0f : q[0])
                 : (j == L) ? (hi ? q[L - 1] : 0.0f)
                            : (hi ? q[j - 1] : q[j]);
        s[j] = bs;
        q[j] = bq;
    }
#pragma unroll
    for (int j = 0; j <= L; ++j) {
        s[j] += shx(s[j], BM);
        q[j] += shx(q[j], BM);
    }
}

// One task = 8 consecutive blocks; this lane's 8 float4s of block blk.
static __device__ __forceinline__ void process_task(
    const f32x4 (&xv)[8], float* __restrict__ out, int blk, int l,
    bool p1, bool p2, bool hi1, bool hi2, bool hi4,
    const float (&wg)[9], const float (&bg)[9])
{
    constexpr int PC8[8] = {0,1,1,2,1,2,2,3};
    const float invc[9] = {1.0f, 0.125f, 1.0f/28.0f, 1.0f/56.0f, 1.0f/70.0f,
                           1.0f/56.0f, 1.0f/28.0f, 0.125f, 1.0f};

    float s[9], q[9];
#pragma unroll
    for (int j = 0; j < 9; ++j) { s[j] = 0.0f; q[j] = 0.0f; }

#define ACC1(v, r) { s[r] += (v); q[r] = fmaf((v), (v), q[r]); }
#pragma unroll
    for (int k = 0; k < 8; ++k) {
        const int r = PC8[k];
        ACC1(xv[k][0], r + 0)
        ACC1(xv[k][1], r + 1)
        ACC1(xv[k][2], r + 1)
        ACC1(xv[k][3], r + 2)
    }
#undef ACC1

    pascal_step<1, 6>(s, q, hi1);
    pascal_step<2, 7>(s, q, hi2);
    pascal_step<4, 8>(s, q, hi4);
    // s[g], q[g] = per-grade sum / sum-of-squares for this group's block

    float scl[9], sft[9];
#pragma unroll
    for (int g = 0; g < 9; ++g) {
        float mean = s[g] * invc[g];
        float var  = fmaf(-mean, mean, q[g] * invc[g]);
        var = fmaxf(var, 0.0f);
        float inv = rsqrtf(var + 1e-5f);
        float sc  = inv * wg[g];
        scl[g] = sc;
        sft[g] = fmaf(-mean, sc, bg[g]);
    }

    // shift down by p = pc(l) in 0..3; only relative grades 0..5 consumed
#pragma unroll
    for (int j = 0; j < 7; ++j) { scl[j] = p2 ? scl[j+2] : scl[j];
                                  sft[j] = p2 ? sft[j+2] : sft[j]; }
#pragma unroll
    for (int j = 0; j < 6; ++j) { scl[j] = p1 ? scl[j+1] : scl[j];
                                  sft[j] = p1 ? sft[j+1] : sft[j]; }

    f32x4* ob = reinterpret_cast<f32x4*>(out) + (size_t)blk * 64;
#pragma unroll
    for (int k = 0; k < 8; ++k) {
        const int r = PC8[k];
        f32x4 o;
        o[0] = fmaf(xv[k][0], scl[r + 0], sft[r + 0]);
        o[1] = fmaf(xv[k][1], scl[r + 1], sft[r + 1]);
        o[2] = fmaf(xv[k][2], scl[r + 1], sft[r + 1]);
        o[3] = fmaf(xv[k][3], scl[r + 2], sft[r + 2]);
        __builtin_nontemporal_store(o, &ob[8 * k + l]);
    }
}

#define LOADT(buf, task) { \
    const f32x4* xb = reinterpret_cast<const f32x4*>(x) + \
        ((size_t)(((task) << 3) + grp)) * 64; \
    _Pragma("unroll") \
    for (int k = 0; k < 8; ++k) buf[k] = xb[8 * k + l]; }

// Fast path: ntask even, one wave per 2 consecutive tasks (16 blocks).
__global__ __launch_bounds__(256) void cliff_ln_flat(
    const float* __restrict__ x, const float* __restrict__ w,
    const float* __restrict__ b, float* __restrict__ out, int nwaves)
{
    const int lane = threadIdx.x & 63;
    const int grp  = lane >> 3;   // 8 groups of 8 lanes
    const int l    = lane & 7;
    const int p    = __popc(l);
    const bool p1 = (p & 1) != 0, p2 = (p & 2) != 0;
    const bool hi1 = (l & 1) != 0, hi2 = (l & 2) != 0, hi4 = (l & 4) != 0;
    const int wid = (blockIdx.x * blockDim.x + threadIdx.x) >> 6;
    if (wid >= nwaves) return;
    const int tA = wid * 2, tB = tA + 1;

    float wg[9], bg[9];
#pragma unroll
    for (int g = 0; g < 9; ++g) { wg[g] = w[g]; bg[g] = b[g]; }

    f32x4 A[8], B[8];
    LOADT(A, tA)
    LOADT(B, tB)
    __builtin_amdgcn_sched_barrier(0);
    process_task(A, out, (tA << 3) + grp, l, p1, p2, hi1, hi2, hi4, wg, bg);
    process_task(B, out, (tB << 3) + grp, l, p1, p2, hi1, hi2, hi4, wg, bg);
}

// General fallback: grid-stride, 1 task per wave, guarded for partial tasks.
__global__ __launch_bounds__(256) void cliff_ln_loop(
    const float* __restrict__ x, const float* __restrict__ w,
    const float* __restrict__ b, float* __restrict__ out, int nblk)
{
    const int lane = threadIdx.x & 63;
    const int grp  = lane >> 3;
    const int l    = lane & 7;
    const int p    = __popc(l);
    const bool p1 = (p & 1) != 0, p2 = (p & 2) != 0;
    const bool hi1 = (l & 1) != 0, hi2 = (l & 2) != 0, hi4 = (l & 4) != 0;
    const int wave_id     = (blockIdx.x * blockDim.x + threadIdx.x) >> 6;
    const int total_waves = (gridDim.x * blockDim.x) >> 6;

    float wg[9], bg[9];
#pragma unroll
    for (int g = 0; g < 9; ++g) { wg[g] = w[g]; bg[g] = b[g]; }

    const int ntask = (nblk + 7) >> 3;
    for (int task = wave_id; task < ntask; task += total_waves) {
        const int blk = (task << 3) + grp;
        f32x4 A[8];
        if (blk < nblk) {
            const f32x4* xb = reinterpret_cast<const f32x4*>(x) + (size_t)blk * 64;
#pragma unroll
            for (int k = 0; k < 8; ++k) A[k] = xb[8 * k + l];
        } else {
#pragma unroll
            for (int k = 0; k < 8; ++k) A[k] = f32x4{0.f, 0.f, 0.f, 0.f};
        }
        if (blk < nblk)
            process_task(A, out, blk, l, p1, p2, hi1, hi2, hi4, wg, bg);
    }
}

#undef LOADT

extern "C" void kernel_launch(void* const* d_in, const int* in_sizes, int n_in,
                              void* d_out, int out_size, void* d_ws, size_t ws_size,
                              hipStream_t stream) {
    const float* x = (const float*)d_in[0];
    const float* w = (const float*)d_in[1];
    const float* b = (const float*)d_in[2];
    float* out = (float*)d_out;
    const int n = in_sizes[0];
    const int nblk = n / 256;
    const int ntask = nblk / 8;             // 32768 for the bench shape

    if ((nblk % 8 == 0) && (ntask % 2 == 0)) {
        const int nwaves = ntask / 2;       // 16384
        const int wgs = (nwaves + 3) / 4;   // 4096 WGs
        hipLaunchKernelGGL(cliff_ln_flat, dim3(wgs), dim3(256), 0, stream,
                           x, w, b, out, nwaves);
    } else {
        int wgs = ((nblk + 7) / 8 + 3) / 4;
        if (wgs > 8192) wgs = 8192;
        if (wgs < 1) wgs = 1;
        hipLaunchKernelGGL(cliff_ln_loop, dim3(wgs), dim3(256), 0, stream,
                           x, w, b, out, nblk);
    }
}

// Round 11
// 83.998 us; speedup vs baseline: 1.5700x; 1.0172x over previous
//
#include <hip/hip_runtime.h>

// CliffordLayerNorm: per-256-float block, per-grade (popcount) layernorm.
// 8 lanes per MV block (8 blocks/wave). Lane l (0..7) of a group holds the
// 8 float4s f = 8k + l -> elements m = 32k + 4l + j, popcount(m) =
// pc(k)+pc(l)+pc(j). Relative grades 0..5 above base p = pc(l) (0..3).
// 3-step Pascal butterfly (6 -> 7 -> 8 -> 9). 128B-aligned full-line
// loads/stores per 8-lane group (R10: killed NT write inflation, 85.4us).
//
// Round-11: dataflow-forced depth-2. Order: loadA, loadB, statsA, statsB,
// finishA+storeA, finishB+storeB. B's stats precede A's stores, so B's
// loads can't be sunk past them (R10's VGPR=48 proved the compiler was
// serializing waitA/computeA/waitB/computeB). statsA || statsB are two
// independent chains -> 2-way ILP through the shuffle-latency-bound
// Pascal phase. NT stores kept (R8: +35%; write stream must not thrash L2).

typedef float f32x4 __attribute__((ext_vector_type(4)));

static __device__ __forceinline__ float shx(float v, int m) {
    return __shfl_xor(v, m, 64);
}

template <int BM, int L>
static __device__ __forceinline__ void pascal_step(float (&s)[9], float (&q)[9],
                                                   bool hi) {
#pragma unroll
    for (int j = L; j >= 0; --j) {
        float bs = (j == 0) ? (hi ? 0.0f : s[0])
                 : (j == L) ? (hi ? s[L - 1] : 0.0f)
                            : (hi ? s[j - 1] : s[j]);
        float bq = (j == 0) ? (hi ? 0.0f : q[0])
                 : (j == L) ? (hi ? q[L - 1] : 0.0f)
                            : (hi ? q[j - 1] : q[j]);
        s[j] = bs;
        q[j] = bq;
    }
#pragma unroll
    for (int j = 0; j <= L; ++j) {
        s[j] += shx(s[j], BM);
        q[j] += shx(q[j], BM);
    }
}

// Per-grade sum/sumsq for one task's 8 float4s (8 consecutive blocks/group).
static __device__ __forceinline__ void stats_task(
    const f32x4 (&xv)[8], float (&s)[9], float (&q)[9],
    bool hi1, bool hi2, bool hi4)
{
    constexpr int PC8[8] = {0,1,1,2,1,2,2,3};
#pragma unroll
    for (int j = 0; j < 9; ++j) { s[j] = 0.0f; q[j] = 0.0f; }
#define ACC1(v, r) { s[r] += (v); q[r] = fmaf((v), (v), q[r]); }
#pragma unroll
    for (int k = 0; k < 8; ++k) {
        const int r = PC8[k];
        ACC1(xv[k][0], r + 0)
        ACC1(xv[k][1], r + 1)
        ACC1(xv[k][2], r + 1)
        ACC1(xv[k][3], r + 2)
    }
#undef ACC1
    pascal_step<1, 6>(s, q, hi1);
    pascal_step<2, 7>(s, q, hi2);
    pascal_step<4, 8>(s, q, hi4);
}

// Scale/shift extraction + normalize + NT stores for one task.
static __device__ __forceinline__ void finish_task(
    const f32x4 (&xv)[8], const float (&s)[9], const float (&q)[9],
    float* __restrict__ out, int blk, int l, bool p1, bool p2,
    const float (&wg)[9], const float (&bg)[9])
{
    constexpr int PC8[8] = {0,1,1,2,1,2,2,3};
    const float invc[9] = {1.0f, 0.125f, 1.0f/28.0f, 1.0f/56.0f, 1.0f/70.0f,
                           1.0f/56.0f, 1.0f/28.0f, 0.125f, 1.0f};
    float scl[9], sft[9];
#pragma unroll
    for (int g = 0; g < 9; ++g) {
        float mean = s[g] * invc[g];
        float var  = fmaf(-mean, mean, q[g] * invc[g]);
        var = fmaxf(var, 0.0f);
        float inv = rsqrtf(var + 1e-5f);
        float sc  = inv * wg[g];
        scl[g] = sc;
        sft[g] = fmaf(-mean, sc, bg[g]);
    }
#pragma unroll
    for (int j = 0; j < 7; ++j) { scl[j] = p2 ? scl[j+2] : scl[j];
                                  sft[j] = p2 ? sft[j+2] : sft[j]; }
#pragma unroll
    for (int j = 0; j < 6; ++j) { scl[j] = p1 ? scl[j+1] : scl[j];
                                  sft[j] = p1 ? sft[j+1] : sft[j]; }

    f32x4* ob = reinterpret_cast<f32x4*>(out) + (size_t)blk * 64;
#pragma unroll
    for (int k = 0; k < 8; ++k) {
        const int r = PC8[k];
        f32x4 o;
        o[0] = fmaf(xv[k][0], scl[r + 0], sft[r + 0]);
        o[1] = fmaf(xv[k][1], scl[r + 1], sft[r + 1]);
        o[2] = fmaf(xv[k][2], scl[r + 1], sft[r + 1]);
        o[3] = fmaf(xv[k][3], scl[r + 2], sft[r + 2]);
        __builtin_nontemporal_store(o, &ob[8 * k + l]);
    }
}

#define LOADT(buf, task) { \
    const f32x4* xb = reinterpret_cast<const f32x4*>(x) + \
        ((size_t)(((task) << 3) + grp)) * 64; \
    _Pragma("unroll") \
    for (int k = 0; k < 8; ++k) buf[k] = xb[8 * k + l]; }

// Fast path: ntask even, one wave per 2 consecutive tasks (16 blocks).
__global__ __launch_bounds__(256) void cliff_ln_flat(
    const float* __restrict__ x, const float* __restrict__ w,
    const float* __restrict__ b, float* __restrict__ out, int nwaves)
{
    const int lane = threadIdx.x & 63;
    const int grp  = lane >> 3;
    const int l    = lane & 7;
    const int p    = __popc(l);
    const bool p1 = (p & 1) != 0, p2 = (p & 2) != 0;
    const bool hi1 = (l & 1) != 0, hi2 = (l & 2) != 0, hi4 = (l & 4) != 0;
    const int wid = (blockIdx.x * blockDim.x + threadIdx.x) >> 6;
    if (wid >= nwaves) return;
    const int tA = wid * 2, tB = tA + 1;

    float wg[9], bg[9];
#pragma unroll
    for (int g = 0; g < 9; ++g) { wg[g] = w[g]; bg[g] = b[g]; }

    f32x4 A[8], B[8];
    LOADT(A, tA)
    LOADT(B, tB)
    // stats for BOTH tasks before any store: B's loads are data-depended
    // before A's stores -> compiler must keep full depth-2 residency.
    float sA[9], qA[9], sB[9], qB[9];
    stats_task(A, sA, qA, hi1, hi2, hi4);
    stats_task(B, sB, qB, hi1, hi2, hi4);
    finish_task(A, sA, qA, out, (tA << 3) + grp, l, p1, p2, wg, bg);
    finish_task(B, sB, qB, out, (tB << 3) + grp, l, p1, p2, wg, bg);
}

// General fallback: grid-stride, 1 task per wave, guarded for partial tasks.
__global__ __launch_bounds__(256) void cliff_ln_loop(
    const float* __restrict__ x, const float* __restrict__ w,
    const float* __restrict__ b, float* __restrict__ out, int nblk)
{
    const int lane = threadIdx.x & 63;
    const int grp  = lane >> 3;
    const int l    = lane & 7;
    const int p    = __popc(l);
    const bool p1 = (p & 1) != 0, p2 = (p & 2) != 0;
    const bool hi1 = (l & 1) != 0, hi2 = (l & 2) != 0, hi4 = (l & 4) != 0;
    const int wave_id     = (blockIdx.x * blockDim.x + threadIdx.x) >> 6;
    const int total_waves = (gridDim.x * blockDim.x) >> 6;

    float wg[9], bg[9];
#pragma unroll
    for (int g = 0; g < 9; ++g) { wg[g] = w[g]; bg[g] = b[g]; }

    const int ntask = (nblk + 7) >> 3;
    for (int task = wave_id; task < ntask; task += total_waves) {
        const int blk = (task << 3) + grp;
        if (blk < nblk) {
            const f32x4* xb = reinterpret_cast<const f32x4*>(x) + (size_t)blk * 64;
            f32x4 A[8];
#pragma unroll
            for (int k = 0; k < 8; ++k) A[k] = xb[8 * k + l];
            float sA[9], qA[9];
            stats_task(A, sA, qA, hi1, hi2, hi4);
            finish_task(A, sA, qA, out, blk, l, p1, p2, wg, bg);
        }
    }
}

#undef LOADT

extern "C" void kernel_launch(void* const* d_in, const int* in_sizes, int n_in,
                              void* d_out, int out_size, void* d_ws, size_t ws_size,
                              hipStream_t stream) {
    const float* x = (const float*)d_in[0];
    const float* w = (const float*)d_in[1];
    const float* b = (const float*)d_in[2];
    float* out = (float*)d_out;
    const int n = in_sizes[0];
    const int nblk = n / 256;
    const int ntask = nblk / 8;             // 32768 for the bench shape

    if ((nblk % 8 == 0) && (ntask % 2 == 0)) {
        const int nwaves = ntask / 2;       // 16384
        const int wgs = (nwaves + 3) / 4;   // 4096 WGs
        hipLaunchKernelGGL(cliff_ln_flat, dim3(wgs), dim3(256), 0, stream,
                           x, w, b, out, nwaves);
    } else {
        int wgs = ((nblk + 7) / 8 + 3) / 4;
        if (wgs > 8192) wgs = 8192;
        if (wgs < 1) wgs = 1;
        hipLaunchKernelGGL(cliff_ln_loop, dim3(wgs), dim3(256), 0, stream,
                           x, w, b, out, nblk);
    }
}